// Round 3
// baseline (62773.438 us; speedup 1.0000x reference)
//
#include <hip/hip_runtime.h>
#include <cstdint>
#include <cstddef>

// Problem constants
#define T_ 256
#define B_ 64
#define E_ 256
#define H_ 512
#define NTAG 32
#define CHK 32            // time-chunk length (T_/CHK rec launches per layer)

// ---------------- workspace layout (float offsets), total ~226.6 MB ----------------
// x0: [T][E/4=64][B][4]
static constexpr size_t OX0  = 0;
static constexpr size_t SX0  = (size_t)T_*64*B_*4;            // 4,194,304
// x1: [T][1024/4=256][B][4]   layer-0 output
static constexpr size_t OX1  = OX0 + SX0;
static constexpr size_t SX1  = (size_t)T_*256*B_*4;           // 16,777,216
// x2: [T][1024/4=256][B][4]   layer-1 output (NO aliasing with x1 — round-2 bug)
static constexpr size_t OX2  = OX1 + SX1;
static constexpr size_t SX2  = SX1;
// xp: [2 dir][CHK][2048][B]  chunk staging of gate preactivations
static constexpr size_t OXP  = OX2 + SX2;
static constexpr size_t SXPC = (size_t)CHK*2048*B_;           // 4,194,304 per dir
static constexpr size_t SXP  = 2*SXPC;
// whh packs: [2 dir][256 g][512 k][8 jj] per layer
static constexpr size_t OWHH0 = OXP + SXP;
static constexpr size_t SWHH  = (size_t)2*256*512*8;          // 2,097,152
static constexpr size_t OWHH1 = OWHH0 + SWHH;
// wih packs: [2 dir][128 g][K][16 jj]
static constexpr size_t OWIH0 = OWHH1 + SWHH;
static constexpr size_t SWIH0 = (size_t)2*2048*256;           // 1,048,576
static constexpr size_t OWIH1 = OWIH0 + SWIH0;
static constexpr size_t SWIH1 = (size_t)2*2048*1024;          // 4,194,304
// wout pack: [1024 k][32]
static constexpr size_t OWOUT = OWIH1 + SWIH1;
static constexpr size_t SWOUT = (size_t)1024*32;
// hbuf: [2 layer][2 dir][2 ping][128 k4][64 b][4]
static constexpr size_t OHB   = OWOUT + SWOUT;
static constexpr size_t SHB   = (size_t)2*2*2*128*64*4;       // 262,144
// cbuf: [2 layer][2 dir][512 u][64 b]
static constexpr size_t OCB   = OHB + SHB;
static constexpr size_t SCB   = (size_t)2*2*512*64;           // 131,072
// barrier counters: 16 launches x 32-int stride
static constexpr size_t OBAR  = OCB + SCB;
static constexpr size_t SBAR  = 1024;
// feats: [T][B][32]
static constexpr size_t OFE   = OBAR + SBAR;
static constexpr size_t SFE   = (size_t)T_*B_*NTAG;           // 524,288
// backpointers (bytes): [255][B][32]
static constexpr size_t OBP   = OFE + SFE;
static constexpr size_t SBP   = (size_t)T_*B_*NTAG/4;
static constexpr size_t WS_FLOATS = OBP + SBP;                // 56,656,896 floats = 226.6 MB

__device__ __forceinline__ float sigf(float x){ return 1.0f/(1.0f + expf(-x)); }

// ---------------- weight packing ----------------
// whh pack: out[g][k][jj], jj = gate*2 + uu, row = gate*512 + g*2 + uu
__global__ void pack_whh(const float* __restrict__ w, float* __restrict__ out){
  int id = blockIdx.x*256 + threadIdx.x;            // 2048*512 = 1,048,576 per launch
  int k = id & 511, jj = (id>>9)&7, g = id>>12;
  int row = (jj>>1)*H_ + g*2 + (jj&1);
  out[((size_t)g*512 + k)*8 + jj] = w[(size_t)row*H_ + k];
}
// wih pack: out[g][k][jj] jj in [0,16), row = g*16+jj
__global__ void pack_wih(const float* __restrict__ w, float* __restrict__ out, int K, int kshift){
  int id = blockIdx.x*256 + threadIdx.x;            // 2048*K threads
  int k = id & (K-1); int jj = (id>>kshift)&15; int g = id>>(kshift+4);
  out[((size_t)g*K + k)*16 + jj] = w[(size_t)(g*16+jj)*K + k];
}
// wout pack: out[k][32]
__global__ void pack_wout(const float* __restrict__ w, float* __restrict__ out){
  int id = blockIdx.x*256 + threadIdx.x;            // 32*1024
  int k = id & 1023, jj = id>>10;
  out[k*32 + jj] = w[id];
}

// ---------------- embedding gather (to [t][e4][b][4]) ----------------
__global__ void gather_emb(const int* __restrict__ sent, const float* __restrict__ emb,
                           float* __restrict__ x0){
  int t = blockIdx.x; int lane = threadIdx.x & 63; int w = threadIdx.x >> 6;
  int s = sent[t*B_ + lane];
  const float4* er = (const float4*)emb + (size_t)s*(E_/4);
  float4* xo = (float4*)x0 + (size_t)t*64*64;
  #pragma unroll
  for (int q=0; q<16; ++q){
    int e4 = w*16 + q;
    xo[e4*64 + lane] = er[e4];
  }
}

// ---------------- input projection GEMM (per time-chunk) ----------------
// xp[dir][i][row][b] = sum_k W[row,k]*x[t,k,b] + b_ih[row] + b_hh[row]
// dir f: t = t0+i ; dir r: t = T-1-(t0+i)   (reverse-chronological slots)
// grid (CHK, 64, 2), block 256. Block tile: 32 rows, k split 4 ways over waves.
__global__ __launch_bounds__(256) void proj_kernel(
    const float* __restrict__ xin, const float* __restrict__ wpack,
    const float* __restrict__ bihf, const float* __restrict__ bhhf,
    const float* __restrict__ bihr, const float* __restrict__ bhhr,
    float* __restrict__ xp, int K, int t0){
  int i = blockIdx.x, jg = blockIdx.y, dir = blockIdx.z;
  int t = dir ? (T_-1 - (t0 + i)) : (t0 + i);
  int lane = threadIdx.x & 63;
  int w = __builtin_amdgcn_readfirstlane((int)threadIdx.x) >> 6;
  int kq = K >> 2;                 // k per wave
  int n4 = kq >> 2;                // float4 iters
  int k40 = (w*kq) >> 2;
  const float4* xi = (const float4*)xin + (size_t)t*(K>>2)*64;
  size_t pstride = (size_t)K*16;
  const float* wp = wpack + (size_t)dir*2048*K + (size_t)(jg*2)*pstride + (size_t)w*kq*16;
  float acc[2][16];
  #pragma unroll
  for (int p=0;p<2;p++)
    #pragma unroll
    for (int jj=0;jj<16;jj++) acc[p][jj] = 0.f;
  for (int k4=0; k4<n4; ++k4){
    float4 h = xi[(k40+k4)*64 + lane];
    float hv[4] = {h.x, h.y, h.z, h.w};
    #pragma unroll
    for (int p=0;p<2;p++){
      const float* wv = wp + p*pstride + k4*64;
      #pragma unroll
      for (int ii=0;ii<4;ii++)
        #pragma unroll
        for (int jj=0;jj<16;jj++)
          acc[p][jj] = fmaf(wv[ii*16+jj], hv[ii], acc[p][jj]);
    }
  }
  __shared__ float red[4][32][64];
  #pragma unroll
  for (int p=0;p<2;p++)
    #pragma unroll
    for (int jj=0;jj<16;jj++) red[w][p*16+jj][lane] = acc[p][jj];
  __syncthreads();
  const float* b1 = dir ? bihr : bihf;
  const float* b2 = dir ? bhhr : bhhf;
  float* xpd = xp + (size_t)dir*SXPC + (size_t)i*2048*64;
  #pragma unroll
  for (int q=0;q<8;q++){
    int rr = w*8 + q;
    float v = red[0][rr][lane] + red[1][rr][lane] + red[2][rr][lane] + red[3][rr][lane];
    int row = jg*32 + rr;
    v += b1[row] + b2[row];
    xpd[(size_t)row*64 + lane] = v;
  }
}

// ---------------- persistent bidirectional LSTM (one time-chunk) ----------------
// grid = 512 blocks (dir = bid&1, g = bid>>1 owns units 2g, 2g+1), block 256 (4 waves, k-split).
// All 512 blocks co-resident: 2 blocks/CU (8KB LDS, <=128 VGPR), device-scope barrier per step.
__global__ __launch_bounds__(256,2) void rec_kernel(
    const float* __restrict__ xp, const float* __restrict__ whh,
    float* __restrict__ xout, float* __restrict__ hb0, float* __restrict__ cb0,
    int* __restrict__ bar, int step0, int nsteps){
  int bid = blockIdx.x;
  int dir = bid & 1, g = bid >> 1;
  int lane = threadIdx.x & 63;
  int w = __builtin_amdgcn_readfirstlane((int)threadIdx.x) >> 6;
  const float* xpd = xp + (size_t)dir*SXPC;
  const float* whp = whh + (size_t)dir*(256*512*8) + (size_t)g*(512*8);
  float* hb = hb0 + dir*65536;
  float* cb = cb0 + dir*32768;
  __shared__ float red[4][8][64];
  int u = g*2 + w;   // unit handled by compute waves w<2
  for (int s=0; s<nsteps; ++s){
    int gstep = step0 + s;
    int t = dir ? (T_-1-gstep) : gstep;
    float xpv[4] = {0,0,0,0}; float cprev = 0.f;
    if (w < 2){
      #pragma unroll
      for (int gate=0;gate<4;gate++)
        xpv[gate] = xpd[((size_t)s*2048 + gate*512 + u)*64 + lane];
      cprev = cb[u*64 + lane];
    }
    const float4* hp = (const float4*)(hb + (gstep&1)*32768);  // [128 k4][64 b]
    float acc[8] = {0,0,0,0,0,0,0,0};
    for (int k4=0;k4<32;k4++){
      float4 h = hp[(w*32 + k4)*64 + lane];
      const float* wv = whp + (size_t)(w*128 + k4*4)*8;
      float hv[4] = {h.x, h.y, h.z, h.w};
      #pragma unroll
      for (int ii=0;ii<4;ii++)
        #pragma unroll
        for (int jj=0;jj<8;jj++)
          acc[jj] = fmaf(wv[ii*8+jj], hv[ii], acc[jj]);
    }
    #pragma unroll
    for (int jj=0;jj<8;jj++) red[w][jj][lane] = acc[jj];
    __syncthreads();
    if (w < 2){
      float gv[4];
      #pragma unroll
      for (int gate=0;gate<4;gate++){
        int jj = gate*2 + w;
        gv[gate] = red[0][jj][lane] + red[1][jj][lane] + red[2][jj][lane]
                 + red[3][jj][lane] + xpv[gate];
      }
      float iv = sigf(gv[0]), fv = sigf(gv[1]);
      float gg = tanhf(gv[2]), ov = sigf(gv[3]);
      float c = fv*cprev + iv*gg;
      float h = ov*tanhf(c);
      cb[u*64 + lane] = c;
      float* hw = hb + ((gstep+1)&1)*32768;
      hw[(u>>2)*256 + lane*4 + (u&3)] = h;
      int r = dir*512 + u;
      xout[(size_t)t*65536 + (size_t)(r>>2)*256 + lane*4 + (r&3)] = h;
    }
    if (s < nsteps-1){
      // CORRECT ORDER: flush writes (all threads) -> block barrier -> signal.
      __threadfence();
      __syncthreads();
      if (threadIdx.x == 0){
        __hip_atomic_fetch_add(bar, 1, __ATOMIC_RELEASE, __HIP_MEMORY_SCOPE_AGENT);
        int tgt = 512*(s+1);
        int spins = 0;
        while (__hip_atomic_load(bar, __ATOMIC_ACQUIRE, __HIP_MEMORY_SCOPE_AGENT) < tgt){
          __builtin_amdgcn_s_sleep(8);
          if (++spins > 200000) break;   // failsafe against pathological stall
        }
      }
      __syncthreads();
      __threadfence();   // invalidate before reading the new h ping
    }
  }
}

// ---------------- output projection (feats) ----------------
// feats[t][b][j] = sum_k Wout[j,k]*x2[t,k,b] + b_out[j]; grid 256 (t), block 256.
__global__ __launch_bounds__(256) void feats_kernel(
    const float* __restrict__ x2, const float* __restrict__ wout,
    const float* __restrict__ bout, float* __restrict__ feats){
  int t = blockIdx.x; int lane = threadIdx.x & 63;
  int w = __builtin_amdgcn_readfirstlane((int)threadIdx.x) >> 6;
  const float4* xi = (const float4*)x2 + (size_t)t*16384;
  const float* wp = wout + (size_t)w*256*32;
  float acc[32];
  #pragma unroll
  for (int j=0;j<32;j++) acc[j] = 0.f;
  for (int k4=0;k4<64;k4++){
    float4 h = xi[(w*64 + k4)*64 + lane];
    float hv[4] = {h.x, h.y, h.z, h.w};
    const float* wv = wp + k4*128;
    #pragma unroll
    for (int ii=0;ii<4;ii++)
      #pragma unroll
      for (int j=0;j<32;j++)
        acc[j] = fmaf(wv[ii*32+j], hv[ii], acc[j]);
  }
  __shared__ float red[4][32][64];
  #pragma unroll
  for (int j=0;j<32;j++) red[w][j][lane] = acc[j];
  __syncthreads();
  __shared__ float tr[64*33];
  #pragma unroll
  for (int q=0;q<8;q++){
    int j = w*8 + q;
    float v = red[0][j][lane]+red[1][j][lane]+red[2][j][lane]+red[3][j][lane] + bout[j];
    tr[lane*33 + j] = v;
  }
  __syncthreads();
  float* fo = feats + (size_t)t*2048;
  int tid = threadIdx.x;
  #pragma unroll
  for (int q=0;q<8;q++){
    int idx = tid*8 + q;                 // = b*32 + j
    fo[idx] = tr[(idx>>5)*33 + (idx&31)];
  }
}

// ---------------- Viterbi decode ----------------
// grid 32, block 64: one wave handles 2 batch rows (lane = b_half*32 + j).
__global__ __launch_bounds__(64) void viterbi_kernel(
    const float* __restrict__ feats, const float* __restrict__ trans,
    const float* __restrict__ start, const float* __restrict__ stop,
    unsigned char* __restrict__ bp, float* __restrict__ out){
  int lane = threadIdx.x & 63;
  int b = blockIdx.x*2 + (lane>>5);
  int j = lane & 31;
  int base = lane & 32;
  float tr[32];
  #pragma unroll
  for (int k=0;k<32;k++) tr[k] = trans[j*32+k];
  float dp = start[j] + feats[b*32 + j];
  for (int t=1;t<T_;t++){
    float best = __shfl(dp, base, 64) + tr[0];
    int arg = 0;
    #pragma unroll
    for (int k=1;k<32;k++){
      float v = __shfl(dp, base + k, 64) + tr[k];
      if (v > best){ best = v; arg = k; }
    }
    dp = best + feats[((size_t)t*64 + b)*32 + j];
    bp[(size_t)(t-1)*2048 + b*32 + j] = (unsigned char)arg;
  }
  dp += stop[j];
  float bv = dp; int bi = j;
  #pragma unroll
  for (int off=1; off<32; off<<=1){
    float ov = __shfl_xor(bv, off, 64);
    int oi   = __shfl_xor(bi, off, 64);
    if (ov > bv || (ov == bv && oi < bi)){ bv = ov; bi = oi; }
  }
  if (j == 0){
    out[b] = bv;
    int cur = bi;
    out[64 + 255*64 + b] = (float)cur;
    for (int t=254;t>=0;t--){
      cur = bp[(size_t)t*2048 + b*32 + cur];
      out[64 + t*64 + b] = (float)cur;
    }
  }
}

// ---------------- launcher ----------------
extern "C" void kernel_launch(void* const* d_in, const int* in_sizes, int n_in,
                              void* d_out, int out_size, void* d_ws, size_t ws_size,
                              hipStream_t stream){
  const int*   sent      = (const int*)  d_in[0];
  const float* emb       = (const float*)d_in[1];
  const float* w_ih_l0f  = (const float*)d_in[2];
  const float* w_hh_l0f  = (const float*)d_in[3];
  const float* b_ih_l0f  = (const float*)d_in[4];
  const float* b_hh_l0f  = (const float*)d_in[5];
  const float* w_ih_l0r  = (const float*)d_in[6];
  const float* w_hh_l0r  = (const float*)d_in[7];
  const float* b_ih_l0r  = (const float*)d_in[8];
  const float* b_hh_l0r  = (const float*)d_in[9];
  const float* w_ih_l1f  = (const float*)d_in[10];
  const float* w_hh_l1f  = (const float*)d_in[11];
  const float* b_ih_l1f  = (const float*)d_in[12];
  const float* b_hh_l1f  = (const float*)d_in[13];
  const float* w_ih_l1r  = (const float*)d_in[14];
  const float* w_hh_l1r  = (const float*)d_in[15];
  const float* b_ih_l1r  = (const float*)d_in[16];
  const float* b_hh_l1r  = (const float*)d_in[17];
  const float* W_out     = (const float*)d_in[18];
  const float* b_out     = (const float*)d_in[19];
  const float* trans     = (const float*)d_in[20];
  const float* start_t   = (const float*)d_in[21];
  const float* stop_t    = (const float*)d_in[22];
  float* ws  = (float*)d_ws;
  float* out = (float*)d_out;

  // Guard: if scratch is too small, bail out cleanly (absmax fail, not a GPU fault).
  if (ws_size < WS_FLOATS * sizeof(float)) return;

  // zero h/c/barrier state (ws is re-poisoned to 0xAA before every timed launch)
  hipMemsetAsync(ws + OHB, 0, (SHB + SCB + SBAR)*sizeof(float), stream);

  // weight packing (idempotent, runs every call)
  pack_whh<<<4096,256,0,stream>>>(w_hh_l0f, ws + OWHH0);
  pack_whh<<<4096,256,0,stream>>>(w_hh_l0r, ws + OWHH0 + 1048576);
  pack_whh<<<4096,256,0,stream>>>(w_hh_l1f, ws + OWHH1);
  pack_whh<<<4096,256,0,stream>>>(w_hh_l1r, ws + OWHH1 + 1048576);
  pack_wih<<<2048,256,0,stream>>>(w_ih_l0f, ws + OWIH0,           256, 8);
  pack_wih<<<2048,256,0,stream>>>(w_ih_l0r, ws + OWIH0 + 524288,  256, 8);
  pack_wih<<<8192,256,0,stream>>>(w_ih_l1f, ws + OWIH1,           1024, 10);
  pack_wih<<<8192,256,0,stream>>>(w_ih_l1r, ws + OWIH1 + 2097152, 1024, 10);
  pack_wout<<<128,256,0,stream>>>(W_out, ws + OWOUT);

  gather_emb<<<256,256,0,stream>>>(sent, emb, ws + OX0);

  const int NCH = T_ / CHK;   // 8 chunks per layer
  dim3 gp(CHK, 64, 2);
  int* bar = (int*)(ws + OBAR);

  // layer 0: proj chunk -> rec chunk  (x0 -> x1)
  for (int c = 0; c < NCH; ++c){
    proj_kernel<<<gp,256,0,stream>>>(ws+OX0, ws+OWIH0,
                                     b_ih_l0f,b_hh_l0f,b_ih_l0r,b_hh_l0r,
                                     ws+OXP, 256, c*CHK);
    rec_kernel<<<512,256,0,stream>>>(ws+OXP, ws+OWHH0, ws+OX1,
                                     ws+OHB, ws+OCB, bar + c*32, c*CHK, CHK);
  }
  // layer 1: x1 -> x2 (separate buffer — no aliasing)
  for (int c = 0; c < NCH; ++c){
    proj_kernel<<<gp,256,0,stream>>>(ws+OX1, ws+OWIH1,
                                     b_ih_l1f,b_hh_l1f,b_ih_l1r,b_hh_l1r,
                                     ws+OXP, 1024, c*CHK);
    rec_kernel<<<512,256,0,stream>>>(ws+OXP, ws+OWHH1, ws+OX2,
                                     ws+OHB+131072, ws+OCB+65536,
                                     bar + (NCH + c)*32, c*CHK, CHK);
  }
  // emission scores + decode
  feats_kernel<<<256,256,0,stream>>>(ws+OX2, ws+OWOUT, b_out, ws+OFE);
  viterbi_kernel<<<32,64,0,stream>>>(ws+OFE, trans, start_t, stop_t,
                                     (unsigned char*)(ws+OBP), out);
}

// Round 4
// 35900.537 us; speedup vs baseline: 1.7485x; 1.7485x over previous
//
#include <hip/hip_runtime.h>
#include <cstdint>
#include <cstddef>

// Problem constants
#define T_ 256
#define B_ 64
#define E_ 256
#define H_ 512
#define NTAG 32
#define CHK 32            // time-chunk length (T_/CHK rec launches per layer)

// ---------------- workspace layout (float offsets), total ~226.6 MB ----------------
static constexpr size_t OX0  = 0;
static constexpr size_t SX0  = (size_t)T_*64*B_*4;            // x0 [T][64][B][4]
static constexpr size_t OX1  = OX0 + SX0;
static constexpr size_t SX1  = (size_t)T_*256*B_*4;           // x1 [T][256][B][4]
static constexpr size_t OX2  = OX1 + SX1;
static constexpr size_t SX2  = SX1;                           // x2
static constexpr size_t OXP  = OX2 + SX2;
static constexpr size_t SXPC = (size_t)CHK*2048*B_;           // xp per dir
static constexpr size_t SXP  = 2*SXPC;
// whh packs: per layer: [2 dir][512 u][512 k][4 gate]
static constexpr size_t OWHH0 = OXP + SXP;
static constexpr size_t SWHH  = (size_t)2*512*512*4;          // 2,097,152
static constexpr size_t OWHH1 = OWHH0 + SWHH;
// wih packs: [2 dir][128 g][K][16 jj]
static constexpr size_t OWIH0 = OWHH1 + SWHH;
static constexpr size_t SWIH0 = (size_t)2*2048*256;
static constexpr size_t OWIH1 = OWIH0 + SWIH0;
static constexpr size_t SWIH1 = (size_t)2*2048*1024;
// wout pack: [1024 k][32]
static constexpr size_t OWOUT = OWIH1 + SWIH1;
static constexpr size_t SWOUT = (size_t)1024*32;
// hbuf: [2 layer][2 dir][2 ping][128 k4][64 b][4]
static constexpr size_t OHB   = OWOUT + SWOUT;
static constexpr size_t SHB   = (size_t)2*2*2*128*64*4;       // 262,144
// cbuf: [2 layer][2 dir][512 u][64 b]
static constexpr size_t OCB   = OHB + SHB;
static constexpr size_t SCB   = (size_t)2*2*512*64;
// barrier flags: [2 layer][2 dir][128 blocks x 16 ints]
static constexpr size_t OBAR  = OCB + SCB;
static constexpr size_t SBAR  = (size_t)2*2*128*16;           // 8192 ints
// feats: [T][B][32]
static constexpr size_t OFE   = OBAR + SBAR;
static constexpr size_t SFE   = (size_t)T_*B_*NTAG;
// backpointers (bytes): [255][B][32]
static constexpr size_t OBP   = OFE + SFE;
static constexpr size_t SBP   = (size_t)T_*B_*NTAG/4;
static constexpr size_t WS_FLOATS = OBP + SBP;

__device__ __forceinline__ float sigf(float x){ return 1.0f/(1.0f + expf(-x)); }

// ---------------- weight packing ----------------
// whh pack (per dir matrix): out[(u*512 + k)*4 + gate] = w[(gate*512 + u)*512 + k]
__global__ void pack_whh(const float* __restrict__ w, float* __restrict__ out){
  int id = blockIdx.x*256 + threadIdx.x;            // 1,048,576 per launch (grid 4096)
  int gate = id & 3, k = (id>>2) & 511, u = id >> 11;
  out[id] = w[((size_t)gate*512 + u)*512 + k];
}
// wih pack: out[g][k][jj] jj in [0,16), row = g*16+jj
__global__ void pack_wih(const float* __restrict__ w, float* __restrict__ out, int K, int kshift){
  int id = blockIdx.x*256 + threadIdx.x;            // 2048*K threads
  int k = id & (K-1); int jj = (id>>kshift)&15; int g = id>>(kshift+4);
  out[((size_t)g*K + k)*16 + jj] = w[(size_t)(g*16+jj)*K + k];
}
// wout pack: out[k][32]
__global__ void pack_wout(const float* __restrict__ w, float* __restrict__ out){
  int id = blockIdx.x*256 + threadIdx.x;            // 32*1024
  int k = id & 1023, jj = id>>10;
  out[k*32 + jj] = w[id];
}

// ---------------- embedding gather (to [t][e4][b][4]) ----------------
__global__ void gather_emb(const int* __restrict__ sent, const float* __restrict__ emb,
                           float* __restrict__ x0){
  int t = blockIdx.x; int lane = threadIdx.x & 63; int w = threadIdx.x >> 6;
  int s = sent[t*B_ + lane];
  const float4* er = (const float4*)emb + (size_t)s*(E_/4);
  float4* xo = (float4*)x0 + (size_t)t*64*64;
  #pragma unroll
  for (int q=0; q<16; ++q){
    int e4 = w*16 + q;
    xo[e4*64 + lane] = er[e4];
  }
}

// ---------------- input projection GEMM (per time-chunk) ----------------
// xp[dir][i][row][b] = sum_k W[row,k]*x[t,k,b] + b_ih[row] + b_hh[row]
__global__ __launch_bounds__(256) void proj_kernel(
    const float* __restrict__ xin, const float* __restrict__ wpack,
    const float* __restrict__ bihf, const float* __restrict__ bhhf,
    const float* __restrict__ bihr, const float* __restrict__ bhhr,
    float* __restrict__ xp, int K, int t0){
  int i = blockIdx.x, jg = blockIdx.y, dir = blockIdx.z;
  int t = dir ? (T_-1 - (t0 + i)) : (t0 + i);
  int lane = threadIdx.x & 63;
  int w = __builtin_amdgcn_readfirstlane((int)threadIdx.x) >> 6;
  int kq = K >> 2;                 // k per wave
  int n4 = kq >> 2;                // float4 iters
  int k40 = (w*kq) >> 2;
  const float4* xi = (const float4*)xin + (size_t)t*(K>>2)*64;
  size_t pstride = (size_t)K*16;
  const float* wp = wpack + (size_t)dir*2048*K + (size_t)(jg*2)*pstride + (size_t)w*kq*16;
  float acc[2][16];
  #pragma unroll
  for (int p=0;p<2;p++)
    #pragma unroll
    for (int jj=0;jj<16;jj++) acc[p][jj] = 0.f;
  for (int k4=0; k4<n4; ++k4){
    float4 h = xi[(k40+k4)*64 + lane];
    float hv[4] = {h.x, h.y, h.z, h.w};
    #pragma unroll
    for (int p=0;p<2;p++){
      const float* wv = wp + p*pstride + k4*64;
      #pragma unroll
      for (int ii=0;ii<4;ii++)
        #pragma unroll
        for (int jj=0;jj<16;jj++)
          acc[p][jj] = fmaf(wv[ii*16+jj], hv[ii], acc[p][jj]);
    }
  }
  __shared__ float red[4][32][64];
  #pragma unroll
  for (int p=0;p<2;p++)
    #pragma unroll
    for (int jj=0;jj<16;jj++) red[w][p*16+jj][lane] = acc[p][jj];
  __syncthreads();
  const float* b1 = dir ? bihr : bihf;
  const float* b2 = dir ? bhhr : bhhf;
  float* xpd = xp + (size_t)dir*SXPC + (size_t)i*2048*64;
  #pragma unroll
  for (int q=0;q<8;q++){
    int rr = w*8 + q;
    float v = red[0][rr][lane] + red[1][rr][lane] + red[2][rr][lane] + red[3][rr][lane];
    int row = jg*32 + rr;
    v += b1[row] + b2[row];
    xpd[(size_t)row*64 + lane] = v;
  }
}

// ---------------- persistent bidirectional LSTM (one time-chunk) ----------------
// grid = 256 blocks, 1/CU guaranteed resident (capacity 8/CU). dir = bid&1,
// g = bid>>1 in [0,128). One WAVE owns one unit u = g*4 + wave (all 4 waves compute).
// Weights are wave-uniform (s_load). c-state lives in a register across the chunk.
// Cross-block sync: flag-store barrier (no atomics RMW), per-direction (128 flags),
// monotonic global-step values -> no reset, no ABA.
__global__ __launch_bounds__(256) void rec_kernel(
    const float* __restrict__ xp, const float* __restrict__ whh,
    float* __restrict__ xout, float* __restrict__ hb0, float* __restrict__ cb0,
    int* __restrict__ flags, int step0, int nsteps){
  int bid = blockIdx.x;
  int dir = bid & 1, g = bid >> 1;
  int lane = threadIdx.x & 63;
  int w = __builtin_amdgcn_readfirstlane((int)threadIdx.x >> 6);
  int u = g*4 + w;                              // unit in [0,512)
  const float* xpd = xp + (size_t)dir*SXPC;
  const float4* wv4 = (const float4*)(whh + (size_t)dir*1048576 + (size_t)u*2048); // [k][gate]
  float* hb = hb0 + dir*65536;
  float* cb = cb0 + dir*32768;
  int* fl = flags + dir*(128*16);
  float c = cb[u*64 + lane];                    // carried in register across steps
  for (int s=0; s<nsteps; ++s){
    int gstep = step0 + s;
    int t = dir ? (T_-1-gstep) : gstep;
    const float4* hp = (const float4*)(hb + (gstep&1)*32768);  // [128 k4][64 b]
    float a0=0.f, a1=0.f, a2=0.f, a3=0.f;
    #pragma unroll 8
    for (int k4=0;k4<128;k4++){
      float4 h4 = hp[k4*64 + lane];
      float4 wa = wv4[k4*4+0], wb = wv4[k4*4+1], wc = wv4[k4*4+2], wd = wv4[k4*4+3];
      a0 = fmaf(wa.x, h4.x, a0); a1 = fmaf(wa.y, h4.x, a1);
      a2 = fmaf(wa.z, h4.x, a2); a3 = fmaf(wa.w, h4.x, a3);
      a0 = fmaf(wb.x, h4.y, a0); a1 = fmaf(wb.y, h4.y, a1);
      a2 = fmaf(wb.z, h4.y, a2); a3 = fmaf(wb.w, h4.y, a3);
      a0 = fmaf(wc.x, h4.z, a0); a1 = fmaf(wc.y, h4.z, a1);
      a2 = fmaf(wc.z, h4.z, a2); a3 = fmaf(wc.w, h4.z, a3);
      a0 = fmaf(wd.x, h4.w, a0); a1 = fmaf(wd.y, h4.w, a1);
      a2 = fmaf(wd.z, h4.w, a2); a3 = fmaf(wd.w, h4.w, a3);
    }
    size_t xb = ((size_t)s*2048 + u)*64 + lane;
    float g0 = a0 + xpd[xb];
    float g1 = a1 + xpd[xb + 512*64];
    float g2 = a2 + xpd[xb + 1024*64];
    float g3 = a3 + xpd[xb + 1536*64];
    float iv = sigf(g0), fv = sigf(g1);
    float gg = tanhf(g2), ov = sigf(g3);
    c = fv*c + iv*gg;
    float h = ov*tanhf(c);
    float* hw = hb + ((gstep+1)&1)*32768;
    hw[(u>>2)*256 + lane*4 + (u&3)] = h;
    int r = dir*512 + u;
    xout[(size_t)t*65536 + (size_t)(r>>2)*256 + lane*4 + (r&3)] = h;
    if (s < nsteps-1){
      // release: make h visible, then parallel flag stores (own line each)
      __threadfence();
      __syncthreads();
      if (threadIdx.x == 0)
        __hip_atomic_store(&fl[g*16], gstep+1, __ATOMIC_RELEASE, __HIP_MEMORY_SCOPE_AGENT);
      int tid = threadIdx.x;
      if (tid < 128){
        int target = gstep+1;
        int spins = 0;
        while (__hip_atomic_load(&fl[tid*16], __ATOMIC_ACQUIRE, __HIP_MEMORY_SCOPE_AGENT) < target){
          __builtin_amdgcn_s_sleep(1);
          if (++spins > (1<<21)) break;   // failsafe
        }
      }
      __syncthreads();
      __threadfence();   // acquire side: don't read stale h
    }
  }
  cb[u*64 + lane] = c;   // persist cell state for the next chunk launch
}

// ---------------- output projection (feats) ----------------
__global__ __launch_bounds__(256) void feats_kernel(
    const float* __restrict__ x2, const float* __restrict__ wout,
    const float* __restrict__ bout, float* __restrict__ feats){
  int t = blockIdx.x; int lane = threadIdx.x & 63;
  int w = __builtin_amdgcn_readfirstlane((int)threadIdx.x) >> 6;
  const float4* xi = (const float4*)x2 + (size_t)t*16384;
  const float* wp = wout + (size_t)w*256*32;
  float acc[32];
  #pragma unroll
  for (int j=0;j<32;j++) acc[j] = 0.f;
  for (int k4=0;k4<64;k4++){
    float4 h = xi[(w*64 + k4)*64 + lane];
    float hv[4] = {h.x, h.y, h.z, h.w};
    const float* wv = wp + k4*128;
    #pragma unroll
    for (int ii=0;ii<4;ii++)
      #pragma unroll
      for (int j=0;j<32;j++)
        acc[j] = fmaf(wv[ii*32+j], hv[ii], acc[j]);
  }
  __shared__ float red[4][32][64];
  #pragma unroll
  for (int j=0;j<32;j++) red[w][j][lane] = acc[j];
  __syncthreads();
  __shared__ float tr[64*33];
  #pragma unroll
  for (int q=0;q<8;q++){
    int j = w*8 + q;
    float v = red[0][j][lane]+red[1][j][lane]+red[2][j][lane]+red[3][j][lane] + bout[j];
    tr[lane*33 + j] = v;
  }
  __syncthreads();
  float* fo = feats + (size_t)t*2048;
  int tid = threadIdx.x;
  #pragma unroll
  for (int q=0;q<8;q++){
    int idx = tid*8 + q;                 // = b*32 + j
    fo[idx] = tr[(idx>>5)*33 + (idx&31)];
  }
}

// ---------------- Viterbi decode ----------------
__global__ __launch_bounds__(64) void viterbi_kernel(
    const float* __restrict__ feats, const float* __restrict__ trans,
    const float* __restrict__ start, const float* __restrict__ stop,
    unsigned char* __restrict__ bp, float* __restrict__ out){
  int lane = threadIdx.x & 63;
  int b = blockIdx.x*2 + (lane>>5);
  int j = lane & 31;
  int base = lane & 32;
  float tr[32];
  #pragma unroll
  for (int k=0;k<32;k++) tr[k] = trans[j*32+k];
  float dp = start[j] + feats[b*32 + j];
  for (int t=1;t<T_;t++){
    float best = __shfl(dp, base, 64) + tr[0];
    int arg = 0;
    #pragma unroll
    for (int k=1;k<32;k++){
      float v = __shfl(dp, base + k, 64) + tr[k];
      if (v > best){ best = v; arg = k; }
    }
    dp = best + feats[((size_t)t*64 + b)*32 + j];
    bp[(size_t)(t-1)*2048 + b*32 + j] = (unsigned char)arg;
  }
  dp += stop[j];
  float bv = dp; int bi = j;
  #pragma unroll
  for (int off=1; off<32; off<<=1){
    float ov = __shfl_xor(bv, off, 64);
    int oi   = __shfl_xor(bi, off, 64);
    if (ov > bv || (ov == bv && oi < bi)){ bv = ov; bi = oi; }
  }
  if (j == 0){
    out[b] = bv;
    int cur = bi;
    out[64 + 255*64 + b] = (float)cur;
    for (int t=254;t>=0;t--){
      cur = bp[(size_t)t*2048 + b*32 + cur];
      out[64 + t*64 + b] = (float)cur;
    }
  }
}

// ---------------- launcher ----------------
extern "C" void kernel_launch(void* const* d_in, const int* in_sizes, int n_in,
                              void* d_out, int out_size, void* d_ws, size_t ws_size,
                              hipStream_t stream){
  const int*   sent      = (const int*)  d_in[0];
  const float* emb       = (const float*)d_in[1];
  const float* w_ih_l0f  = (const float*)d_in[2];
  const float* w_hh_l0f  = (const float*)d_in[3];
  const float* b_ih_l0f  = (const float*)d_in[4];
  const float* b_hh_l0f  = (const float*)d_in[5];
  const float* w_ih_l0r  = (const float*)d_in[6];
  const float* w_hh_l0r  = (const float*)d_in[7];
  const float* b_ih_l0r  = (const float*)d_in[8];
  const float* b_hh_l0r  = (const float*)d_in[9];
  const float* w_ih_l1f  = (const float*)d_in[10];
  const float* w_hh_l1f  = (const float*)d_in[11];
  const float* b_ih_l1f  = (const float*)d_in[12];
  const float* b_hh_l1f  = (const float*)d_in[13];
  const float* w_ih_l1r  = (const float*)d_in[14];
  const float* w_hh_l1r  = (const float*)d_in[15];
  const float* b_ih_l1r  = (const float*)d_in[16];
  const float* b_hh_l1r  = (const float*)d_in[17];
  const float* W_out     = (const float*)d_in[18];
  const float* b_out     = (const float*)d_in[19];
  const float* trans     = (const float*)d_in[20];
  const float* start_t   = (const float*)d_in[21];
  const float* stop_t    = (const float*)d_in[22];
  float* ws  = (float*)d_ws;
  float* out = (float*)d_out;

  // Guard: if scratch is too small, bail out cleanly (absmax fail, not a GPU fault).
  if (ws_size < WS_FLOATS * sizeof(float)) return;

  // zero h/c/flag state (ws is re-poisoned to 0xAA before every timed launch)
  hipMemsetAsync(ws + OHB, 0, (SHB + SCB + SBAR)*sizeof(float), stream);

  // weight packing (idempotent, runs every call)
  pack_whh<<<4096,256,0,stream>>>(w_hh_l0f, ws + OWHH0);
  pack_whh<<<4096,256,0,stream>>>(w_hh_l0r, ws + OWHH0 + 1048576);
  pack_whh<<<4096,256,0,stream>>>(w_hh_l1f, ws + OWHH1);
  pack_whh<<<4096,256,0,stream>>>(w_hh_l1r, ws + OWHH1 + 1048576);
  pack_wih<<<2048,256,0,stream>>>(w_ih_l0f, ws + OWIH0,           256, 8);
  pack_wih<<<2048,256,0,stream>>>(w_ih_l0r, ws + OWIH0 + 524288,  256, 8);
  pack_wih<<<8192,256,0,stream>>>(w_ih_l1f, ws + OWIH1,           1024, 10);
  pack_wih<<<8192,256,0,stream>>>(w_ih_l1r, ws + OWIH1 + 2097152, 1024, 10);
  pack_wout<<<128,256,0,stream>>>(W_out, ws + OWOUT);

  gather_emb<<<256,256,0,stream>>>(sent, emb, ws + OX0);

  const int NCH = T_ / CHK;   // 8 chunks per layer
  dim3 gp(CHK, 64, 2);
  int* bar = (int*)(ws + OBAR);

  // layer 0: proj chunk -> rec chunk  (x0 -> x1)
  for (int c = 0; c < NCH; ++c){
    proj_kernel<<<gp,256,0,stream>>>(ws+OX0, ws+OWIH0,
                                     b_ih_l0f,b_hh_l0f,b_ih_l0r,b_hh_l0r,
                                     ws+OXP, 256, c*CHK);
    rec_kernel<<<256,256,0,stream>>>(ws+OXP, ws+OWHH0, ws+OX1,
                                     ws+OHB, ws+OCB, bar, c*CHK, CHK);
  }
  // layer 1: x1 -> x2 (separate buffer)
  for (int c = 0; c < NCH; ++c){
    proj_kernel<<<gp,256,0,stream>>>(ws+OX1, ws+OWIH1,
                                     b_ih_l1f,b_hh_l1f,b_ih_l1r,b_hh_l1r,
                                     ws+OXP, 1024, c*CHK);
    rec_kernel<<<256,256,0,stream>>>(ws+OXP, ws+OWHH1, ws+OX2,
                                     ws+OHB+131072, ws+OCB+65536,
                                     bar + 4096, c*CHK, CHK);
  }
  // emission scores + decode
  feats_kernel<<<256,256,0,stream>>>(ws+OX2, ws+OWOUT, b_out, ws+OFE);
  viterbi_kernel<<<32,64,0,stream>>>(ws+OFE, trans, start_t, stop_t,
                                     (unsigned char*)(ws+OBP), out);
}

// Round 5
// 9112.847 us; speedup vs baseline: 6.8885x; 3.9396x over previous
//
#include <hip/hip_runtime.h>
#include <cstdint>
#include <cstddef>

// Problem constants
#define T_ 256
#define B_ 64
#define E_ 256
#define H_ 512
#define NTAG 32
#define CHK 32            // time-chunk length (T_/CHK rec launches per layer)
#define HSLOT 33          // rolling h-history slots (CHK+1; no address reuse within a launch)

// ---------------- workspace layout (float offsets), total ~226.1 MB ----------------
// x1: [T][256][B][4]  layer-0 output
static constexpr size_t OX1  = 0;
static constexpr size_t SX1  = (size_t)T_*256*B_*4;           // 16,777,216
// x2: [T][256][B][4]  layer-1 output; x0 (embeddings) ALIASES its head:
//   x0 is dead once layer-0 proj is done; layer-1 rec only then starts writing x2.
static constexpr size_t OX2  = OX1 + SX1;
static constexpr size_t SX2  = SX1;
static constexpr size_t OX0  = OX2;                           // [T][64][B][4] = 4,194,304 floats
// xp: [2 dir][CHK][2048][B]
static constexpr size_t OXP  = OX2 + SX2;
static constexpr size_t SXPC = (size_t)CHK*2048*B_;           // 4,194,304 per dir
static constexpr size_t SXP  = 2*SXPC;
// whh packs: per layer: [2 dir][512 u][512 k][4 gate]
static constexpr size_t OWHH0 = OXP + SXP;
static constexpr size_t SWHH  = (size_t)2*512*512*4;          // 2,097,152
static constexpr size_t OWHH1 = OWHH0 + SWHH;
// wih packs: [2 dir][128 g][K][16 jj]
static constexpr size_t OWIH0 = OWHH1 + SWHH;
static constexpr size_t SWIH0 = (size_t)2*2048*256;
static constexpr size_t OWIH1 = OWIH0 + SWIH0;
static constexpr size_t SWIH1 = (size_t)2*2048*1024;
// wout pack: [1024 k][32]
static constexpr size_t OWOUT = OWIH1 + SWIH1;
static constexpr size_t SWOUT = (size_t)1024*32;
// h history: [2 layer][2 dir][HSLOT][128 k4][64 b][4]
static constexpr size_t OHH   = OWOUT + SWOUT;
static constexpr size_t SHHL  = (size_t)2*HSLOT*32768;        // per layer (2 dir)
static constexpr size_t SHH   = 2*SHHL;                       // 4,325,376
// cbuf: [2 layer][2 dir][512 u][64 b]
static constexpr size_t OCB   = OHH + SHH;
static constexpr size_t SCB   = (size_t)2*2*512*64;
// barrier flags: [2 layer][2 dir][128 blocks x 16 ints]
static constexpr size_t OBAR  = OCB + SCB;
static constexpr size_t SBAR  = (size_t)2*2*128*16;           // 8192 ints
// feats: [T][B][32]
static constexpr size_t OFE   = OBAR + SBAR;
static constexpr size_t SFE   = (size_t)T_*B_*NTAG;
// backpointers (bytes): [255][B][32]
static constexpr size_t OBP   = OFE + SFE;
static constexpr size_t SBP   = (size_t)T_*B_*NTAG/4;
static constexpr size_t WS_FLOATS = OBP + SBP;                // 56,532,992 floats = 226.1 MB

__device__ __forceinline__ float sigf(float x){ return 1.0f/(1.0f + expf(-x)); }

// ---------------- weight packing ----------------
// whh pack (per dir matrix): out[(u*512 + k)*4 + gate] = w[(gate*512 + u)*512 + k]
__global__ void pack_whh(const float* __restrict__ w, float* __restrict__ out){
  int id = blockIdx.x*256 + threadIdx.x;            // grid 4096
  int gate = id & 3, k = (id>>2) & 511, u = id >> 11;
  out[id] = w[((size_t)gate*512 + u)*512 + k];
}
// wih pack: out[g][k][jj] jj in [0,16), row = g*16+jj
__global__ void pack_wih(const float* __restrict__ w, float* __restrict__ out, int K, int kshift){
  int id = blockIdx.x*256 + threadIdx.x;            // 2048*K threads
  int k = id & (K-1); int jj = (id>>kshift)&15; int g = id>>(kshift+4);
  out[((size_t)g*K + k)*16 + jj] = w[(size_t)(g*16+jj)*K + k];
}
// wout pack: out[k][32]
__global__ void pack_wout(const float* __restrict__ w, float* __restrict__ out){
  int id = blockIdx.x*256 + threadIdx.x;            // 32*1024
  int k = id & 1023, jj = id>>10;
  out[k*32 + jj] = w[id];
}

// ---------------- embedding gather (to [t][e4][b][4]) ----------------
__global__ void gather_emb(const int* __restrict__ sent, const float* __restrict__ emb,
                           float* __restrict__ x0){
  int t = blockIdx.x; int lane = threadIdx.x & 63; int w = threadIdx.x >> 6;
  int s = sent[t*B_ + lane];
  const float4* er = (const float4*)emb + (size_t)s*(E_/4);
  float4* xo = (float4*)x0 + (size_t)t*64*64;
  #pragma unroll
  for (int q=0; q<16; ++q){
    int e4 = w*16 + q;
    xo[e4*64 + lane] = er[e4];
  }
}

// ---------------- input projection GEMM (per time-chunk) ----------------
__global__ __launch_bounds__(256) void proj_kernel(
    const float* __restrict__ xin, const float* __restrict__ wpack,
    const float* __restrict__ bihf, const float* __restrict__ bhhf,
    const float* __restrict__ bihr, const float* __restrict__ bhhr,
    float* __restrict__ xp, int K, int t0){
  int i = blockIdx.x, jg = blockIdx.y, dir = blockIdx.z;
  int t = dir ? (T_-1 - (t0 + i)) : (t0 + i);
  int lane = threadIdx.x & 63;
  int w = __builtin_amdgcn_readfirstlane((int)threadIdx.x) >> 6;
  int kq = K >> 2;                 // k per wave
  int n4 = kq >> 2;                // float4 iters
  int k40 = (w*kq) >> 2;
  const float4* xi = (const float4*)xin + (size_t)t*(K>>2)*64;
  size_t pstride = (size_t)K*16;
  const float* wp = wpack + (size_t)dir*2048*K + (size_t)(jg*2)*pstride + (size_t)w*kq*16;
  float acc[2][16];
  #pragma unroll
  for (int p=0;p<2;p++)
    #pragma unroll
    for (int jj=0;jj<16;jj++) acc[p][jj] = 0.f;
  for (int k4=0; k4<n4; ++k4){
    float4 h = xi[(k40+k4)*64 + lane];
    float hv[4] = {h.x, h.y, h.z, h.w};
    #pragma unroll
    for (int p=0;p<2;p++){
      const float* wv = wp + p*pstride + k4*64;
      #pragma unroll
      for (int ii=0;ii<4;ii++)
        #pragma unroll
        for (int jj=0;jj<16;jj++)
          acc[p][jj] = fmaf(wv[ii*16+jj], hv[ii], acc[p][jj]);
    }
  }
  __shared__ float red[4][32][64];
  #pragma unroll
  for (int p=0;p<2;p++)
    #pragma unroll
    for (int jj=0;jj<16;jj++) red[w][p*16+jj][lane] = acc[p][jj];
  __syncthreads();
  const float* b1 = dir ? bihr : bihf;
  const float* b2 = dir ? bhhr : bhhf;
  float* xpd = xp + (size_t)dir*SXPC + (size_t)i*2048*64;
  #pragma unroll
  for (int q=0;q<8;q++){
    int rr = w*8 + q;
    float v = red[0][rr][lane] + red[1][rr][lane] + red[2][rr][lane] + red[3][rr][lane];
    int row = jg*32 + rr;
    v += b1[row] + b2[row];
    xpd[(size_t)row*64 + lane] = v;
  }
}

// ---------------- persistent bidirectional LSTM (one time-chunk) ----------------
// grid = 256 blocks (1/CU). dir = bid&1, g = bid>>1 in [0,128). One wave owns unit
// u = g*4 + w; c-state in a register. FENCE-FREE protocol:
//  - h published via relaxed agent atomic stores (write-through to coherent LLC)
//  - s_waitcnt vmcnt(0) == completion at coherence point, then relaxed flag store
//  - readers poll flags with relaxed atomic loads (NO buffer_inv -> weights stay cached)
//  - h read with plain loads from a rolling 33-slot history: no address reuse within
//    a launch, so no stale line can ever be hit; lines enter caches only post-flag.
__global__ __launch_bounds__(256) void rec_kernel(
    const float* __restrict__ xp, const float* __restrict__ whh,
    float* __restrict__ xout, float* __restrict__ hh, float* __restrict__ cb0,
    int* __restrict__ flags, int step0, int nsteps){
  int bid = blockIdx.x;
  int dir = bid & 1, g = bid >> 1;
  int lane = threadIdx.x & 63;
  int w = __builtin_amdgcn_readfirstlane((int)threadIdx.x >> 6);
  int u = g*4 + w;                              // unit in [0,512)
  const float* xpd = xp + (size_t)dir*SXPC;
  const float4* wv4 = (const float4*)(whh + (size_t)dir*1048576 + (size_t)u*2048); // [k][gate]
  float* hhd = hh + (size_t)dir*((size_t)HSLOT*32768);
  float* cb = cb0 + dir*32768;
  int* fl = flags + dir*(128*16);
  __shared__ float hlds[256];                   // [64 b][4 u] assembled h quad
  float c = cb[u*64 + lane];
  // preload xp gates for step 0
  size_t xb = ((size_t)u)*64 + lane;
  float x0v = xpd[xb], x1v = xpd[xb+512*64], x2v = xpd[xb+1024*64], x3v = xpd[xb+1536*64];
  for (int s=0; s<nsteps; ++s){
    int gstep = step0 + s;
    int t = dir ? (T_-1-gstep) : gstep;
    const float4* hp = (const float4*)(hhd + (size_t)(gstep % HSLOT)*32768);
    float a0=0.f, a1=0.f, a2=0.f, a3=0.f;
    #pragma unroll 8
    for (int k4=0;k4<128;k4++){
      float4 h4 = hp[k4*64 + lane];
      float4 wa = wv4[k4*4+0], wb = wv4[k4*4+1], wc = wv4[k4*4+2], wd = wv4[k4*4+3];
      a0 = fmaf(wa.x, h4.x, a0); a1 = fmaf(wa.y, h4.x, a1);
      a2 = fmaf(wa.z, h4.x, a2); a3 = fmaf(wa.w, h4.x, a3);
      a0 = fmaf(wb.x, h4.y, a0); a1 = fmaf(wb.y, h4.y, a1);
      a2 = fmaf(wb.z, h4.y, a2); a3 = fmaf(wb.w, h4.y, a3);
      a0 = fmaf(wc.x, h4.z, a0); a1 = fmaf(wc.y, h4.z, a1);
      a2 = fmaf(wc.z, h4.z, a2); a3 = fmaf(wc.w, h4.z, a3);
      a0 = fmaf(wd.x, h4.w, a0); a1 = fmaf(wd.y, h4.w, a1);
      a2 = fmaf(wd.z, h4.w, a2); a3 = fmaf(wd.w, h4.w, a3);
    }
    float g0 = a0 + x0v, g1 = a1 + x1v, g2 = a2 + x2v, g3 = a3 + x3v;
    float iv = sigf(g0), fv = sigf(g1);
    float gg = tanhf(g2), ov = sigf(g3);
    c = fv*c + iv*gg;
    float h = ov*tanhf(c);
    hlds[lane*4 + w] = h;
    __syncthreads();
    if (w == 0){
      // publish h quad: contiguous write-through coherent stores (2x u64 per lane)
      float4 hv4 = ((const float4*)hlds)[lane];
      union { float4 f; unsigned long long q[2]; } uu; uu.f = hv4;
      unsigned long long* dst = (unsigned long long*)
          (hhd + (size_t)((gstep+1) % HSLOT)*32768 + (size_t)g*256 + (size_t)lane*4);
      __hip_atomic_store(dst+0, uu.q[0], __ATOMIC_RELAXED, __HIP_MEMORY_SCOPE_AGENT);
      __hip_atomic_store(dst+1, uu.q[1], __ATOMIC_RELAXED, __HIP_MEMORY_SCOPE_AGENT);
    } else if (w == 1){
      // xout tile: plain coalesced float4 (kernel-boundary flush covers consumers)
      float4 hv4 = ((const float4*)hlds)[lane];
      float4* xo = (float4*)(xout + (size_t)t*65536 + (size_t)(dir*128 + g)*256);
      xo[lane] = hv4;
    }
    if (s < nsteps-1){
      if (w == 0){
        asm volatile("s_waitcnt vmcnt(0)" ::: "memory");   // h stores at coherence point
      }
      __syncthreads();
      if (threadIdx.x == 0)
        __hip_atomic_store(&fl[g*16], gstep+1, __ATOMIC_RELAXED, __HIP_MEMORY_SCOPE_AGENT);
      // prefetch next step's xp gates (overlaps poll latency)
      size_t xb2 = ((size_t)(s+1)*2048 + u)*64 + lane;
      x0v = xpd[xb2]; x1v = xpd[xb2+512*64]; x2v = xpd[xb2+1024*64]; x3v = xpd[xb2+1536*64];
      int tid = threadIdx.x;
      if (tid < 128){
        int target = gstep+1;
        int spins = 0;
        while (__hip_atomic_load(&fl[tid*16], __ATOMIC_RELAXED, __HIP_MEMORY_SCOPE_AGENT) < target){
          __builtin_amdgcn_s_sleep(1);
          if (++spins > (1<<22)) break;   // failsafe
        }
      }
      __syncthreads();
      asm volatile("" ::: "memory");      // keep h loads after the poll
    }
  }
  cb[u*64 + lane] = c;   // persist cell state for the next chunk launch
}

// ---------------- output projection (feats) ----------------
__global__ __launch_bounds__(256) void feats_kernel(
    const float* __restrict__ x2, const float* __restrict__ wout,
    const float* __restrict__ bout, float* __restrict__ feats){
  int t = blockIdx.x; int lane = threadIdx.x & 63;
  int w = __builtin_amdgcn_readfirstlane((int)threadIdx.x) >> 6;
  const float4* xi = (const float4*)x2 + (size_t)t*16384;
  const float* wp = wout + (size_t)w*256*32;
  float acc[32];
  #pragma unroll
  for (int j=0;j<32;j++) acc[j] = 0.f;
  for (int k4=0;k4<64;k4++){
    float4 h = xi[(w*64 + k4)*64 + lane];
    float hv[4] = {h.x, h.y, h.z, h.w};
    const float* wv = wp + k4*128;
    #pragma unroll
    for (int ii=0;ii<4;ii++)
      #pragma unroll
      for (int j=0;j<32;j++)
        acc[j] = fmaf(wv[ii*32+j], hv[ii], acc[j]);
  }
  __shared__ float red[4][32][64];
  #pragma unroll
  for (int j=0;j<32;j++) red[w][j][lane] = acc[j];
  __syncthreads();
  __shared__ float tr[64*33];
  #pragma unroll
  for (int q=0;q<8;q++){
    int j = w*8 + q;
    float v = red[0][j][lane]+red[1][j][lane]+red[2][j][lane]+red[3][j][lane] + bout[j];
    tr[lane*33 + j] = v;
  }
  __syncthreads();
  float* fo = feats + (size_t)t*2048;
  int tid = threadIdx.x;
  #pragma unroll
  for (int q=0;q<8;q++){
    int idx = tid*8 + q;                 // = b*32 + j
    fo[idx] = tr[(idx>>5)*33 + (idx&31)];
  }
}

// ---------------- Viterbi decode ----------------
__global__ __launch_bounds__(64) void viterbi_kernel(
    const float* __restrict__ feats, const float* __restrict__ trans,
    const float* __restrict__ start, const float* __restrict__ stop,
    unsigned char* __restrict__ bp, float* __restrict__ out){
  int lane = threadIdx.x & 63;
  int b = blockIdx.x*2 + (lane>>5);
  int j = lane & 31;
  int base = lane & 32;
  float tr[32];
  #pragma unroll
  for (int k=0;k<32;k++) tr[k] = trans[j*32+k];
  float dp = start[j] + feats[b*32 + j];
  for (int t=1;t<T_;t++){
    float best = __shfl(dp, base, 64) + tr[0];
    int arg = 0;
    #pragma unroll
    for (int k=1;k<32;k++){
      float v = __shfl(dp, base + k, 64) + tr[k];
      if (v > best){ best = v; arg = k; }
    }
    dp = best + feats[((size_t)t*64 + b)*32 + j];
    bp[(size_t)(t-1)*2048 + b*32 + j] = (unsigned char)arg;
  }
  dp += stop[j];
  float bv = dp; int bi = j;
  #pragma unroll
  for (int off=1; off<32; off<<=1){
    float ov = __shfl_xor(bv, off, 64);
    int oi   = __shfl_xor(bi, off, 64);
    if (ov > bv || (ov == bv && oi < bi)){ bv = ov; bi = oi; }
  }
  if (j == 0){
    out[b] = bv;
    int cur = bi;
    out[64 + 255*64 + b] = (float)cur;
    for (int t=254;t>=0;t--){
      cur = bp[(size_t)t*2048 + b*32 + cur];
      out[64 + t*64 + b] = (float)cur;
    }
  }
}

// ---------------- launcher ----------------
extern "C" void kernel_launch(void* const* d_in, const int* in_sizes, int n_in,
                              void* d_out, int out_size, void* d_ws, size_t ws_size,
                              hipStream_t stream){
  const int*   sent      = (const int*)  d_in[0];
  const float* emb       = (const float*)d_in[1];
  const float* w_ih_l0f  = (const float*)d_in[2];
  const float* w_hh_l0f  = (const float*)d_in[3];
  const float* b_ih_l0f  = (const float*)d_in[4];
  const float* b_hh_l0f  = (const float*)d_in[5];
  const float* w_ih_l0r  = (const float*)d_in[6];
  const float* w_hh_l0r  = (const float*)d_in[7];
  const float* b_ih_l0r  = (const float*)d_in[8];
  const float* b_hh_l0r  = (const float*)d_in[9];
  const float* w_ih_l1f  = (const float*)d_in[10];
  const float* w_hh_l1f  = (const float*)d_in[11];
  const float* b_ih_l1f  = (const float*)d_in[12];
  const float* b_hh_l1f  = (const float*)d_in[13];
  const float* w_ih_l1r  = (const float*)d_in[14];
  const float* w_hh_l1r  = (const float*)d_in[15];
  const float* b_ih_l1r  = (const float*)d_in[16];
  const float* b_hh_l1r  = (const float*)d_in[17];
  const float* W_out     = (const float*)d_in[18];
  const float* b_out     = (const float*)d_in[19];
  const float* trans     = (const float*)d_in[20];
  const float* start_t   = (const float*)d_in[21];
  const float* stop_t    = (const float*)d_in[22];
  float* ws  = (float*)d_ws;
  float* out = (float*)d_out;

  // Guard: if scratch is too small, bail out cleanly (absmax fail, not a GPU fault).
  if (ws_size < WS_FLOATS * sizeof(float)) return;

  // zero h-history/c/flag state (ws is re-poisoned to 0xAA before every timed launch)
  hipMemsetAsync(ws + OHH, 0, (SHH + SCB + SBAR)*sizeof(float), stream);

  // weight packing (idempotent, runs every call)
  pack_whh<<<4096,256,0,stream>>>(w_hh_l0f, ws + OWHH0);
  pack_whh<<<4096,256,0,stream>>>(w_hh_l0r, ws + OWHH0 + 1048576);
  pack_whh<<<4096,256,0,stream>>>(w_hh_l1f, ws + OWHH1);
  pack_whh<<<4096,256,0,stream>>>(w_hh_l1r, ws + OWHH1 + 1048576);
  pack_wih<<<2048,256,0,stream>>>(w_ih_l0f, ws + OWIH0,           256, 8);
  pack_wih<<<2048,256,0,stream>>>(w_ih_l0r, ws + OWIH0 + 524288,  256, 8);
  pack_wih<<<8192,256,0,stream>>>(w_ih_l1f, ws + OWIH1,           1024, 10);
  pack_wih<<<8192,256,0,stream>>>(w_ih_l1r, ws + OWIH1 + 2097152, 1024, 10);
  pack_wout<<<128,256,0,stream>>>(W_out, ws + OWOUT);

  gather_emb<<<256,256,0,stream>>>(sent, emb, ws + OX0);

  const int NCH = T_ / CHK;   // 8 chunks per layer
  dim3 gp(CHK, 64, 2);
  int* bar = (int*)(ws + OBAR);

  // layer 0: proj chunk -> rec chunk  (x0 -> x1)
  for (int c = 0; c < NCH; ++c){
    proj_kernel<<<gp,256,0,stream>>>(ws+OX0, ws+OWIH0,
                                     b_ih_l0f,b_hh_l0f,b_ih_l0r,b_hh_l0r,
                                     ws+OXP, 256, c*CHK);
    rec_kernel<<<256,256,0,stream>>>(ws+OXP, ws+OWHH0, ws+OX1,
                                     ws+OHH, ws+OCB, bar, c*CHK, CHK);
  }
  // layer 1: x1 -> x2 (x0 alias is dead by now)
  for (int c = 0; c < NCH; ++c){
    proj_kernel<<<gp,256,0,stream>>>(ws+OX1, ws+OWIH1,
                                     b_ih_l1f,b_hh_l1f,b_ih_l1r,b_hh_l1r,
                                     ws+OXP, 1024, c*CHK);
    rec_kernel<<<256,256,0,stream>>>(ws+OXP, ws+OWHH1, ws+OX2,
                                     ws+OHH+SHHL, ws+OCB+65536,
                                     bar + 4096, c*CHK, CHK);
  }
  // emission scores + decode
  feats_kernel<<<256,256,0,stream>>>(ws+OX2, ws+OWOUT, b_out, ws+OFE);
  viterbi_kernel<<<32,64,0,stream>>>(ws+OFE, trans, start_t, stop_t,
                                     (unsigned char*)(ws+OBP), out);
}

// Round 6
// 8939.874 us; speedup vs baseline: 7.0217x; 1.0193x over previous
//
#include <hip/hip_runtime.h>
#include <cstdint>
#include <cstddef>

// Problem constants
#define T_ 256
#define B_ 64
#define E_ 256
#define H_ 512
#define NTAG 32
#define CHK 32            // time-chunk length (T_/CHK rec launches per layer)
#define HSLOT 33          // rolling h-history slots (CHK+1; no address reuse within a launch)

// ---------------- workspace layout (float offsets), total ~226.1 MB ----------------
// x1: [T][256][B][4]  layer-0 output
static constexpr size_t OX1  = 0;
static constexpr size_t SX1  = (size_t)T_*256*B_*4;           // 16,777,216
// x2: [T][256][B][4]  layer-1 output; x0 (embeddings) ALIASES its head
static constexpr size_t OX2  = OX1 + SX1;
static constexpr size_t SX2  = SX1;
static constexpr size_t OX0  = OX2;                           // [T][64][B][4]
// xp: [2 dir][CHK][2048][B]
static constexpr size_t OXP  = OX2 + SX2;
static constexpr size_t SXPC = (size_t)CHK*2048*B_;           // 4,194,304 per dir
static constexpr size_t SXP  = 2*SXPC;
// whh packs: per layer: [2 dir][512 u][512 k][4 gate]
static constexpr size_t OWHH0 = OXP + SXP;
static constexpr size_t SWHH  = (size_t)2*512*512*4;          // 2,097,152
static constexpr size_t OWHH1 = OWHH0 + SWHH;
// wih packs: [2 dir][128 g][K][16 jj]
static constexpr size_t OWIH0 = OWHH1 + SWHH;
static constexpr size_t SWIH0 = (size_t)2*2048*256;
static constexpr size_t OWIH1 = OWIH0 + SWIH0;
static constexpr size_t SWIH1 = (size_t)2*2048*1024;
// wout pack: [1024 k][32]
static constexpr size_t OWOUT = OWIH1 + SWIH1;
static constexpr size_t SWOUT = (size_t)1024*32;
// h history: [2 layer][2 dir][HSLOT][128 k4][64 b][4]
static constexpr size_t OHH   = OWOUT + SWOUT;
static constexpr size_t SHHL  = (size_t)2*HSLOT*32768;        // per layer (2 dir)
static constexpr size_t SHH   = 2*SHHL;
// cbuf: [2 layer][2 dir][512 u][64 b]
static constexpr size_t OCB   = OHH + SHH;
static constexpr size_t SCB   = (size_t)2*2*512*64;
// barrier flags: [2 layer][2 dir][128 blocks x 16 ints]
static constexpr size_t OBAR  = OCB + SCB;
static constexpr size_t SBAR  = (size_t)2*2*128*16;           // 8192 ints
// feats: [T][B][32]
static constexpr size_t OFE   = OBAR + SBAR;
static constexpr size_t SFE   = (size_t)T_*B_*NTAG;
// backpointers (bytes): [255][B][32]
static constexpr size_t OBP   = OFE + SFE;
static constexpr size_t SBP   = (size_t)T_*B_*NTAG/4;
static constexpr size_t WS_FLOATS = OBP + SBP;                // ~226.1 MB

__device__ __forceinline__ float sigf(float x){ return 1.0f/(1.0f + expf(-x)); }

// ---------------- weight packing ----------------
// whh pack (per dir matrix): out[(u*512 + k)*4 + gate] = w[(gate*512 + u)*512 + k]
__global__ void pack_whh(const float* __restrict__ w, float* __restrict__ out){
  int id = blockIdx.x*256 + threadIdx.x;            // grid 4096
  int gate = id & 3, k = (id>>2) & 511, u = id >> 11;
  out[id] = w[((size_t)gate*512 + u)*512 + k];
}
// wih pack: out[g][k][jj] jj in [0,16), row = g*16+jj
__global__ void pack_wih(const float* __restrict__ w, float* __restrict__ out, int K, int kshift){
  int id = blockIdx.x*256 + threadIdx.x;            // 2048*K threads
  int k = id & (K-1); int jj = (id>>kshift)&15; int g = id>>(kshift+4);
  out[((size_t)g*K + k)*16 + jj] = w[(size_t)(g*16+jj)*K + k];
}
// wout pack: out[k][32]
__global__ void pack_wout(const float* __restrict__ w, float* __restrict__ out){
  int id = blockIdx.x*256 + threadIdx.x;            // 32*1024
  int k = id & 1023, jj = id>>10;
  out[k*32 + jj] = w[id];
}

// ---------------- embedding gather (to [t][e4][b][4]) ----------------
__global__ void gather_emb(const int* __restrict__ sent, const float* __restrict__ emb,
                           float* __restrict__ x0){
  int t = blockIdx.x; int lane = threadIdx.x & 63; int w = threadIdx.x >> 6;
  int s = sent[t*B_ + lane];
  const float4* er = (const float4*)emb + (size_t)s*(E_/4);
  float4* xo = (float4*)x0 + (size_t)t*64*64;
  #pragma unroll
  for (int q=0; q<16; ++q){
    int e4 = w*16 + q;
    xo[e4*64 + lane] = er[e4];
  }
}

// ---------------- input projection GEMM (per time-chunk) ----------------
// Grid (jg=64, i=CHK, dir=2): jg fastest-varying so each W-slice is pinned to one
// XCD (id%8 == jg%8) and stays L2-resident across t; 64 same-t blocks are adjacent
// so x[t] is fetched ~once per XCD instead of once per block.
__global__ __launch_bounds__(256) void proj_kernel(
    const float* __restrict__ xin, const float* __restrict__ wpack,
    const float* __restrict__ bihf, const float* __restrict__ bhhf,
    const float* __restrict__ bihr, const float* __restrict__ bhhr,
    float* __restrict__ xp, int K, int t0){
  int jg = blockIdx.x, i = blockIdx.y, dir = blockIdx.z;
  int t = dir ? (T_-1 - (t0 + i)) : (t0 + i);
  int lane = threadIdx.x & 63;
  int w = __builtin_amdgcn_readfirstlane((int)threadIdx.x) >> 6;
  int kq = K >> 2;                 // k per wave
  int n4 = kq >> 2;                // float4 iters
  int k40 = (w*kq) >> 2;
  const float4* xi = (const float4*)xin + (size_t)t*(K>>2)*64;
  size_t pstride = (size_t)K*16;
  const float* wp = wpack + (size_t)dir*2048*K + (size_t)(jg*2)*pstride + (size_t)w*kq*16;
  float acc[2][16];
  #pragma unroll
  for (int p=0;p<2;p++)
    #pragma unroll
    for (int jj=0;jj<16;jj++) acc[p][jj] = 0.f;
  for (int k4=0; k4<n4; ++k4){
    float4 h = xi[(k40+k4)*64 + lane];
    float hv[4] = {h.x, h.y, h.z, h.w};
    #pragma unroll
    for (int p=0;p<2;p++){
      const float* wv = wp + p*pstride + k4*64;
      #pragma unroll
      for (int ii=0;ii<4;ii++)
        #pragma unroll
        for (int jj=0;jj<16;jj++)
          acc[p][jj] = fmaf(wv[ii*16+jj], hv[ii], acc[p][jj]);
    }
  }
  __shared__ float red[4][32][64];
  #pragma unroll
  for (int p=0;p<2;p++)
    #pragma unroll
    for (int jj=0;jj<16;jj++) red[w][p*16+jj][lane] = acc[p][jj];
  __syncthreads();
  const float* b1 = dir ? bihr : bihf;
  const float* b2 = dir ? bhhr : bhhf;
  float* xpd = xp + (size_t)dir*SXPC + (size_t)i*2048*64;
  #pragma unroll
  for (int q=0;q<8;q++){
    int rr = w*8 + q;
    float v = red[0][rr][lane] + red[1][rr][lane] + red[2][rr][lane] + red[3][rr][lane];
    int row = jg*32 + rr;
    v += b1[row] + b2[row];
    xpd[(size_t)row*64 + lane] = v;
  }
}

// ---------------- persistent bidirectional LSTM (one time-chunk) ----------------
// grid = 256 blocks (1/CU). dir = bid&1, g = bid>>1 in [0,128). K-SPLIT layout:
// wave w loads its 128-k quarter of h into 32 float4 REGISTERS (one latency
// exposure, 32 loads in flight), computes partials for all 4 units x 4 gates,
// LDS-reduce across waves, wave w finalizes unit uo = g*4+w (c in register).
// Fence-free flag protocol as round 5 (relaxed agent atomics + vmcnt(0), rolling
// 33-slot h history; kernel-boundary implicit acquire/release handles reuse).
__global__ __launch_bounds__(256,1) void rec_kernel(
    const float* __restrict__ xp, const float* __restrict__ whh,
    float* __restrict__ xout, float* __restrict__ hh, float* __restrict__ cb0,
    int* __restrict__ flags, int step0, int nsteps){
  int bid = blockIdx.x;
  int dir = bid & 1, g = bid >> 1;
  int lane = threadIdx.x & 63;
  int w = __builtin_amdgcn_readfirstlane((int)threadIdx.x >> 6);
  const float* xpd = xp + (size_t)dir*SXPC;
  const float* wbase = whh + (size_t)dir*1048576 + (size_t)g*4*2048;  // [u][k][gate]
  float* hhd = hh + (size_t)dir*((size_t)HSLOT*32768);
  float* cb = cb0 + dir*32768;
  int* fl = flags + dir*(128*16);
  __shared__ float red[4][16][64];              // [wave][u*4+gate][lane]
  __shared__ float hlds[256];                   // [64 b][4 u]
  int uo = g*4 + w;                             // unit finalized by this wave
  float c = cb[uo*64 + lane];
  size_t xb = ((size_t)uo)*64 + lane;
  float x0v = xpd[xb], x1v = xpd[xb+32768], x2v = xpd[xb+65536], x3v = xpd[xb+98304];
  for (int s=0; s<nsteps; ++s){
    int gstep = step0 + s;
    int t = dir ? (T_-1-gstep) : gstep;
    const float4* hp = (const float4*)(hhd + (size_t)(gstep % HSLOT)*32768);
    // stage this wave's k-quarter into registers: 32 independent loads in flight
    float4 hreg[32];
    #pragma unroll
    for (int i=0;i<32;i++) hreg[i] = hp[(w*32+i)*64 + lane];
    float acc[4][4];
    #pragma unroll
    for (int cu=0;cu<4;cu++)
      #pragma unroll
      for (int gt=0;gt<4;gt++) acc[cu][gt]=0.f;
    #pragma unroll
    for (int i=0;i<32;i++){
      float hv[4] = {hreg[i].x, hreg[i].y, hreg[i].z, hreg[i].w};
      #pragma unroll
      for (int cu=0; cu<4; cu++){
        const float4* wr = (const float4*)(wbase + (size_t)cu*2048 + (size_t)(w*128 + i*4)*4);
        #pragma unroll
        for (int kk=0;kk<4;kk++){
          float4 w4 = wr[kk];
          acc[cu][0] = fmaf(w4.x, hv[kk], acc[cu][0]);
          acc[cu][1] = fmaf(w4.y, hv[kk], acc[cu][1]);
          acc[cu][2] = fmaf(w4.z, hv[kk], acc[cu][2]);
          acc[cu][3] = fmaf(w4.w, hv[kk], acc[cu][3]);
        }
      }
    }
    #pragma unroll
    for (int cu=0;cu<4;cu++)
      #pragma unroll
      for (int gt=0;gt<4;gt++) red[w][cu*4+gt][lane] = acc[cu][gt];
    __syncthreads();
    float gv[4];
    #pragma unroll
    for (int gt=0;gt<4;gt++)
      gv[gt] = red[0][w*4+gt][lane] + red[1][w*4+gt][lane]
             + red[2][w*4+gt][lane] + red[3][w*4+gt][lane];
    gv[0] += x0v; gv[1] += x1v; gv[2] += x2v; gv[3] += x3v;
    float iv = sigf(gv[0]), fv = sigf(gv[1]);
    float gg = tanhf(gv[2]), ov = sigf(gv[3]);
    c = fv*c + iv*gg;
    float h = ov*tanhf(c);
    hlds[lane*4 + w] = h;
    __syncthreads();
    if (w == 0){
      // publish h quad: write-through coherent stores (2x u64 per lane = 1 KB)
      float4 hv4 = ((const float4*)hlds)[lane];
      union { float4 f; unsigned long long q[2]; } uu; uu.f = hv4;
      unsigned long long* dst = (unsigned long long*)
          (hhd + (size_t)((gstep+1) % HSLOT)*32768 + (size_t)g*256 + (size_t)lane*4);
      __hip_atomic_store(dst+0, uu.q[0], __ATOMIC_RELAXED, __HIP_MEMORY_SCOPE_AGENT);
      __hip_atomic_store(dst+1, uu.q[1], __ATOMIC_RELAXED, __HIP_MEMORY_SCOPE_AGENT);
    } else if (w == 1){
      float4 hv4 = ((const float4*)hlds)[lane];
      float4* xo = (float4*)(xout + (size_t)t*65536 + (size_t)(dir*128 + g)*256);
      xo[lane] = hv4;
    }
    if (s < nsteps-1){
      if (w == 0){
        asm volatile("s_waitcnt vmcnt(0)" ::: "memory");   // h stores at coherence point
      }
      __syncthreads();
      if (threadIdx.x == 0)
        __hip_atomic_store(&fl[g*16], gstep+1, __ATOMIC_RELAXED, __HIP_MEMORY_SCOPE_AGENT);
      // prefetch next step's xp gates (overlaps poll latency)
      size_t xb2 = ((size_t)(s+1)*2048 + uo)*64 + lane;
      x0v = xpd[xb2]; x1v = xpd[xb2+32768]; x2v = xpd[xb2+65536]; x3v = xpd[xb2+98304];
      int tid = threadIdx.x;
      if (tid < 128){
        int target = gstep+1;
        int spins = 0;
        while (__hip_atomic_load(&fl[tid*16], __ATOMIC_RELAXED, __HIP_MEMORY_SCOPE_AGENT) < target){
          __builtin_amdgcn_s_sleep(1);
          if (++spins > (1<<22)) break;   // failsafe
        }
      }
      __syncthreads();
      asm volatile("" ::: "memory");      // keep h loads after the poll
    }
  }
  cb[uo*64 + lane] = c;   // persist cell state for the next chunk launch
}

// ---------------- output projection (feats) ----------------
__global__ __launch_bounds__(256) void feats_kernel(
    const float* __restrict__ x2, const float* __restrict__ wout,
    const float* __restrict__ bout, float* __restrict__ feats){
  int t = blockIdx.x; int lane = threadIdx.x & 63;
  int w = __builtin_amdgcn_readfirstlane((int)threadIdx.x) >> 6;
  const float4* xi = (const float4*)x2 + (size_t)t*16384;
  const float* wp = wout + (size_t)w*256*32;
  float acc[32];
  #pragma unroll
  for (int j=0;j<32;j++) acc[j] = 0.f;
  for (int k4=0;k4<64;k4++){
    float4 h = xi[(w*64 + k4)*64 + lane];
    float hv[4] = {h.x, h.y, h.z, h.w};
    const float* wv = wp + k4*128;
    #pragma unroll
    for (int ii=0;ii<4;ii++)
      #pragma unroll
      for (int j=0;j<32;j++)
        acc[j] = fmaf(wv[ii*32+j], hv[ii], acc[j]);
  }
  __shared__ float red[4][32][64];
  #pragma unroll
  for (int j=0;j<32;j++) red[w][j][lane] = acc[j];
  __syncthreads();
  __shared__ float tr[64*33];
  #pragma unroll
  for (int q=0;q<8;q++){
    int j = w*8 + q;
    float v = red[0][j][lane]+red[1][j][lane]+red[2][j][lane]+red[3][j][lane] + bout[j];
    tr[lane*33 + j] = v;
  }
  __syncthreads();
  float* fo = feats + (size_t)t*2048;
  int tid = threadIdx.x;
  #pragma unroll
  for (int q=0;q<8;q++){
    int idx = tid*8 + q;                 // = b*32 + j
    fo[idx] = tr[(idx>>5)*33 + (idx&31)];
  }
}

// ---------------- Viterbi decode ----------------
__global__ __launch_bounds__(64) void viterbi_kernel(
    const float* __restrict__ feats, const float* __restrict__ trans,
    const float* __restrict__ start, const float* __restrict__ stop,
    unsigned char* __restrict__ bp, float* __restrict__ out){
  int lane = threadIdx.x & 63;
  int b = blockIdx.x*2 + (lane>>5);
  int j = lane & 31;
  int base = lane & 32;
  float tr[32];
  #pragma unroll
  for (int k=0;k<32;k++) tr[k] = trans[j*32+k];
  float dp = start[j] + feats[b*32 + j];
  for (int t=1;t<T_;t++){
    float best = __shfl(dp, base, 64) + tr[0];
    int arg = 0;
    #pragma unroll
    for (int k=1;k<32;k++){
      float v = __shfl(dp, base + k, 64) + tr[k];
      if (v > best){ best = v; arg = k; }
    }
    dp = best + feats[((size_t)t*64 + b)*32 + j];
    bp[(size_t)(t-1)*2048 + b*32 + j] = (unsigned char)arg;
  }
  dp += stop[j];
  float bv = dp; int bi = j;
  #pragma unroll
  for (int off=1; off<32; off<<=1){
    float ov = __shfl_xor(bv, off, 64);
    int oi   = __shfl_xor(bi, off, 64);
    if (ov > bv || (ov == bv && oi < bi)){ bv = ov; bi = oi; }
  }
  if (j == 0){
    out[b] = bv;
    int cur = bi;
    out[64 + 255*64 + b] = (float)cur;
    for (int t=254;t>=0;t--){
      cur = bp[(size_t)t*2048 + b*32 + cur];
      out[64 + t*64 + b] = (float)cur;
    }
  }
}

// ---------------- launcher ----------------
extern "C" void kernel_launch(void* const* d_in, const int* in_sizes, int n_in,
                              void* d_out, int out_size, void* d_ws, size_t ws_size,
                              hipStream_t stream){
  const int*   sent      = (const int*)  d_in[0];
  const float* emb       = (const float*)d_in[1];
  const float* w_ih_l0f  = (const float*)d_in[2];
  const float* w_hh_l0f  = (const float*)d_in[3];
  const float* b_ih_l0f  = (const float*)d_in[4];
  const float* b_hh_l0f  = (const float*)d_in[5];
  const float* w_ih_l0r  = (const float*)d_in[6];
  const float* w_hh_l0r  = (const float*)d_in[7];
  const float* b_ih_l0r  = (const float*)d_in[8];
  const float* b_hh_l0r  = (const float*)d_in[9];
  const float* w_ih_l1f  = (const float*)d_in[10];
  const float* w_hh_l1f  = (const float*)d_in[11];
  const float* b_ih_l1f  = (const float*)d_in[12];
  const float* b_hh_l1f  = (const float*)d_in[13];
  const float* w_ih_l1r  = (const float*)d_in[14];
  const float* w_hh_l1r  = (const float*)d_in[15];
  const float* b_ih_l1r  = (const float*)d_in[16];
  const float* b_hh_l1r  = (const float*)d_in[17];
  const float* W_out     = (const float*)d_in[18];
  const float* b_out     = (const float*)d_in[19];
  const float* trans     = (const float*)d_in[20];
  const float* start_t   = (const float*)d_in[21];
  const float* stop_t    = (const float*)d_in[22];
  float* ws  = (float*)d_ws;
  float* out = (float*)d_out;

  // Guard: if scratch is too small, bail out cleanly (absmax fail, not a GPU fault).
  if (ws_size < WS_FLOATS * sizeof(float)) return;

  // zero h-history/c/flag state (ws is re-poisoned to 0xAA before every timed launch)
  hipMemsetAsync(ws + OHH, 0, (SHH + SCB + SBAR)*sizeof(float), stream);

  // weight packing (idempotent, runs every call)
  pack_whh<<<4096,256,0,stream>>>(w_hh_l0f, ws + OWHH0);
  pack_whh<<<4096,256,0,stream>>>(w_hh_l0r, ws + OWHH0 + 1048576);
  pack_whh<<<4096,256,0,stream>>>(w_hh_l1f, ws + OWHH1);
  pack_whh<<<4096,256,0,stream>>>(w_hh_l1r, ws + OWHH1 + 1048576);
  pack_wih<<<2048,256,0,stream>>>(w_ih_l0f, ws + OWIH0,           256, 8);
  pack_wih<<<2048,256,0,stream>>>(w_ih_l0r, ws + OWIH0 + 524288,  256, 8);
  pack_wih<<<8192,256,0,stream>>>(w_ih_l1f, ws + OWIH1,           1024, 10);
  pack_wih<<<8192,256,0,stream>>>(w_ih_l1r, ws + OWIH1 + 2097152, 1024, 10);
  pack_wout<<<128,256,0,stream>>>(W_out, ws + OWOUT);

  gather_emb<<<256,256,0,stream>>>(sent, emb, ws + OX0);

  const int NCH = T_ / CHK;   // 8 chunks per layer
  dim3 gp(64, CHK, 2);        // jg fastest: XCD-pinned W-slices, same-t adjacency
  int* bar = (int*)(ws + OBAR);

  // layer 0: proj chunk -> rec chunk  (x0 -> x1)
  for (int c = 0; c < NCH; ++c){
    proj_kernel<<<gp,256,0,stream>>>(ws+OX0, ws+OWIH0,
                                     b_ih_l0f,b_hh_l0f,b_ih_l0r,b_hh_l0r,
                                     ws+OXP, 256, c*CHK);
    rec_kernel<<<256,256,0,stream>>>(ws+OXP, ws+OWHH0, ws+OX1,
                                     ws+OHH, ws+OCB, bar, c*CHK, CHK);
  }
  // layer 1: x1 -> x2 (x0 alias is dead by now)
  for (int c = 0; c < NCH; ++c){
    proj_kernel<<<gp,256,0,stream>>>(ws+OX1, ws+OWIH1,
                                     b_ih_l1f,b_hh_l1f,b_ih_l1r,b_hh_l1r,
                                     ws+OXP, 1024, c*CHK);
    rec_kernel<<<256,256,0,stream>>>(ws+OXP, ws+OWHH1, ws+OX2,
                                     ws+OHH+SHHL, ws+OCB+65536,
                                     bar + 4096, c*CHK, CHK);
  }
  // emission scores + decode
  feats_kernel<<<256,256,0,stream>>>(ws+OX2, ws+OWOUT, b_out, ws+OFE);
  viterbi_kernel<<<32,64,0,stream>>>(ws+OFE, trans, start_t, stop_t,
                                     (unsigned char*)(ws+OBP), out);
}